// Round 5
// baseline (383.353 us; speedup 1.0000x reference)
//
#include <hip/hip_runtime.h>
#include <math.h>

#define NHEADS 16
#define HDIM   64
#define HID    1024
#define BATCH  2
#define SEQ    2048

typedef unsigned short u16;
typedef __attribute__((ext_vector_type(8))) short  bf16x8;   // 8 bf16 = 4 VGPR
typedef __attribute__((ext_vector_type(8))) unsigned short u16x8;
typedef __attribute__((ext_vector_type(4))) float  f32x4;

// async global->LDS, 16B per lane, LDS dest = wave-uniform base + lane*16
#define GLDS(gp, lp)                                                          \
    __builtin_amdgcn_global_load_lds(                                         \
        (const __attribute__((address_space(1))) unsigned int*)(const void*)(gp), \
        (__attribute__((address_space(3))) unsigned int*)(void*)(lp), 16, 0, 0)

// truncation-based fp32 -> bf16(hi) + bf16(lo) split (error ~2^-16 rel)
__device__ __forceinline__ void split8(const float* xf, bf16x8& hi, bf16x8& lo) {
#pragma unroll
    for (int j = 0; j < 8; j++) {
        unsigned u = __float_as_uint(xf[j]);
        hi[j] = (short)(u >> 16);
        float hf = __uint_as_float(u & 0xFFFF0000u);
        lo[j] = (short)(__float_as_uint(xf[j] - hf) >> 16);
    }
}
__device__ __forceinline__ void split1(float v, u16& h, u16& l) {
    unsigned u = __float_as_uint(v);
    h = (u16)(u >> 16);
    l = (u16)(__float_as_uint(v - __uint_as_float(u & 0xFFFF0000u)) >> 16);
}

// ---------------------------------------------------------------------------
// RoPE tables
// ---------------------------------------------------------------------------
__global__ void rope_tables_kernel(float* __restrict__ ct, float* __restrict__ st) {
    int idx = blockIdx.x * 256 + threadIdx.x;
    if (idx >= SEQ * HDIM) return;
    int s  = idx >> 6;
    int dh = idx & 63;
    int i  = dh & 31;
    float inv = exp2f(-(float)i * (13.28771237954945f / 32.0f));  // log2(10000)/32
    float fr  = (float)s * inv;
    ct[idx] = cosf(fr);
    st[idx] = sinf(fr);
}

// ---------------------------------------------------------------------------
// Pre-pass: split X [4096][1024] and W0/1/2 [1024][1024] fp32 -> bf16 hi/lo
// ---------------------------------------------------------------------------
#define NX (BATCH*SEQ*HID)       // 4194304
#define NW (HID*HID)             // 1048576
__global__ void split_kernel(const float* __restrict__ X,
                             const float* __restrict__ W0,
                             const float* __restrict__ W1,
                             const float* __restrict__ W2,
                             u16* __restrict__ Xhi, u16* __restrict__ Xlo,
                             u16* __restrict__ Whi, u16* __restrict__ Wlo)
{
    long idx = ((long)blockIdx.x * 256 + threadIdx.x) * 4;
    if (idx >= (long)NX + 3L * NW) return;
    const float* src; u16* dh; u16* dl; long off;
    if (idx < NX) { src = X; dh = Xhi; dl = Xlo; off = idx; }
    else {
        long r = idx - NX;
        int wi = (int)(r >> 20);
        off = r & (NW - 1);
        src = (wi == 0) ? W0 : ((wi == 1) ? W1 : W2);
        dh = Whi + (size_t)wi * NW;
        dl = Wlo + (size_t)wi * NW;
    }
    float4 v = *(const float4*)(src + off);
    const float* vf = (const float*)&v;
    ushort4 h4, l4;
    u16* hp = (u16*)&h4; u16* lp = (u16*)&l4;
#pragma unroll
    for (int e = 0; e < 4; e++) split1(vf[e], hp[e], lp[e]);
    *(ushort4*)(dh + off) = h4;
    *(ushort4*)(dl + off) = l4;
}

// ---------------------------------------------------------------------------
// MFMA QKV GEMM: C = X @ W^T via split-bf16 3-term emulation.
// m97 structure: global_load_lds(16B) staging into contiguous 64B-pitch
// tiles (LDS byte off = 16*t), 2-barrier K-loop, ds_read_b128 frags.
// C/D mapping (verified R2): m = i*16 + quad*4 + reg, n = j*16 + (lane&15).
// proj 0: Q fp32 [B][NH][S][D] (RoPE)   proj 1: K bf16 hi/lo perm'd (RoPE)
// proj 2: V bf16 hi/lo transposed [B][NH][D][perm(S)] via 2-pass LDS.
// ---------------------------------------------------------------------------
union QkvSmem {
    struct { u16 Ah[128 * 32]; u16 Al[128 * 32]; u16 Bh[128 * 32]; u16 Bl[128 * 32]; } s; // 32 KB
    unsigned vtr[64][129];                                   // 33 KB transpose buf
};

__global__ __launch_bounds__(256, 2) void qkv_mfma_kernel(
    const u16* __restrict__ Xhi, const u16* __restrict__ Xlo,
    const u16* __restrict__ Whi, const u16* __restrict__ Wlo,
    const float* __restrict__ ct, const float* __restrict__ st,
    float* __restrict__ Qo,
    u16* __restrict__ Khi, u16* __restrict__ Klo,
    u16* __restrict__ Vthi, u16* __restrict__ Vtlo)
{
    __shared__ QkvSmem sm;

    const int t    = threadIdx.x;
    const int lane = t & 63;
    const int w    = t >> 6;
    const int lx   = lane & 15;
    const int quad = lane >> 4;
    const int proj = blockIdx.z;
    const int n0   = blockIdx.x * 128;
    const int m0   = blockIdx.y * 128;

    const u16* __restrict__ Wph = Whi + (size_t)proj * NW;
    const u16* __restrict__ Wpl = Wlo + (size_t)proj * NW;

    // staging: thread t <-> flat LDS u16 offset 8*t (row = t>>2, col = (t&3)*8)
    const int r0 = t >> 2;
    const int c0 = (t & 3) * 8;

    const u16* gAh0 = Xhi + (size_t)(m0 + r0) * HID + c0;
    const u16* gAh1 = gAh0 + (size_t)64 * HID;
    const u16* gAl0 = Xlo + (size_t)(m0 + r0) * HID + c0;
    const u16* gAl1 = gAl0 + (size_t)64 * HID;
    const u16* gBh0 = Wph + (size_t)(n0 + r0) * HID + c0;
    const u16* gBh1 = gBh0 + (size_t)64 * HID;
    const u16* gBl0 = Wpl + (size_t)(n0 + r0) * HID + c0;
    const u16* gBl1 = gBl0 + (size_t)64 * HID;

    u16* lAh = sm.s.Ah + 8 * t;
    u16* lAl = sm.s.Al + 8 * t;
    u16* lBh = sm.s.Bh + 8 * t;
    u16* lBl = sm.s.Bl + 8 * t;

    f32x4 acc[4][4];
#pragma unroll
    for (int i = 0; i < 4; i++)
#pragma unroll
        for (int j = 0; j < 4; j++) acc[i][j] = (f32x4){0.f, 0.f, 0.f, 0.f};

    const int am = (w & 1) * 64;
    const int bn = (w >> 1) * 64;

#pragma unroll 1
    for (int kt = 0; kt < HID; kt += 32) {
        __syncthreads();                    // prev tile's frag reads done
        GLDS(gAh0 + kt, lAh);
        GLDS(gAh1 + kt, lAh + 2048);
        GLDS(gAl0 + kt, lAl);
        GLDS(gAl1 + kt, lAl + 2048);
        GLDS(gBh0 + kt, lBh);
        GLDS(gBh1 + kt, lBh + 2048);
        GLDS(gBl0 + kt, lBl);
        GLDS(gBl1 + kt, lBl + 2048);
        __syncthreads();                    // drains vmcnt -> LDS visible

        bf16x8 ah[4], al[4];
#pragma unroll
        for (int i = 0; i < 4; i++) {
            const int r = am + i * 16 + lx;
            ah[i] = *(const bf16x8*)&sm.s.Ah[r * 32 + quad * 8];
            al[i] = *(const bf16x8*)&sm.s.Al[r * 32 + quad * 8];
        }
#pragma unroll
        for (int j = 0; j < 4; j++) {
            const int rn = bn + j * 16 + lx;
            bf16x8 bh = *(const bf16x8*)&sm.s.Bh[rn * 32 + quad * 8];
            bf16x8 bl = *(const bf16x8*)&sm.s.Bl[rn * 32 + quad * 8];
#pragma unroll
            for (int i = 0; i < 4; i++) {
                acc[i][j] = __builtin_amdgcn_mfma_f32_16x16x32_bf16(ah[i], bh, acc[i][j], 0, 0, 0);
                acc[i][j] = __builtin_amdgcn_mfma_f32_16x16x32_bf16(al[i], bh, acc[i][j], 0, 0, 0);
                acc[i][j] = __builtin_amdgcn_mfma_f32_16x16x32_bf16(ah[i], bl, acc[i][j], 0, 0, 0);
            }
        }
    }

    // ---- epilogue ----
    const int b      = m0 >> 11;                 // batch (tiles don't straddle)
    const int head   = (n0 >> 6) + (w >> 1);     // wave's n-half = one head
    const int m_base = m0 + am;

    if (proj < 2) {
        // RoPE in registers: partner dh^32 lives in acc[i][j^2], same lane.
#pragma unroll
        for (int i = 0; i < 4; i++) {
#pragma unroll
            for (int r = 0; r < 4; r++) {
                const int s = (m_base + i * 16 + quad * 4 + r) & 2047;
                const float* ctr = ct + s * HDIM;
                const float* str = st + s * HDIM;
                float nv[4];
#pragma unroll
                for (int j = 0; j < 4; j++) {
                    const int dh = j * 16 + lx;
                    const float c  = ctr[dh];
                    const float sn = str[dh];
                    const float x  = acc[i][j][r];
                    const float p  = acc[i][j ^ 2][r];
                    nv[j] = (j < 2) ? (x * c - p * sn) : (x * c + p * sn);
                }
#pragma unroll
                for (int j = 0; j < 4; j++) acc[i][j][r] = nv[j];
            }
        }
    }

    if (proj == 0) {
        const size_t rowb = (size_t)(b * NHEADS + head) * SEQ;
#pragma unroll
        for (int i = 0; i < 4; i++)
#pragma unroll
            for (int r = 0; r < 4; r++) {
                const int s = (m_base + i * 16 + quad * 4 + r) & 2047;
                float* dst = Qo + (rowb + s) * HDIM;
#pragma unroll
                for (int j = 0; j < 4; j++) dst[j * 16 + lx] = acc[i][j][r];
            }
    } else if (proj == 1) {
        const size_t rowb = (size_t)(b * NHEADS + head) * SEQ;
#pragma unroll
        for (int i = 0; i < 4; i++)
#pragma unroll
            for (int r = 0; r < 4; r++) {
                const int s  = (m_base + i * 16 + quad * 4 + r) & 2047;
                const int sp = s & 7;
                u16* dsth = Khi + (rowb + s) * HDIM;
                u16* dstl = Klo + (rowb + s) * HDIM;
#pragma unroll
                for (int j = 0; j < 4; j++) {
                    const int dh  = j * 16 + lx;
                    const int off = (((dh >> 3) ^ sp) << 3) + (dh & 7);
                    u16 h, l;
                    split1(acc[i][j][r], h, l);
                    dsth[off] = h;
                    dstl[off] = l;
                }
            }
    } else {
        // V: two-pass LDS transpose -> [B][NH][D][perm(S)]
#pragma unroll 1
        for (int pass = 0; pass < 2; pass++) {
            __syncthreads();   // staging reads done (pass 0) / prev pass reads done
            if ((w & 1) == pass) {
#pragma unroll
                for (int i = 0; i < 4; i++)
#pragma unroll
                    for (int j = 0; j < 4; j++)
#pragma unroll
                        for (int r = 0; r < 4; r++) {
                            const int ml = i * 16 + quad * 4 + r;     // 0..63 in pass
                            const int nl = bn + j * 16 + lx;          // 0..127
                            const float v = acc[i][j][r];
                            unsigned u  = __float_as_uint(v);
                            unsigned hi = u & 0xFFFF0000u;
                            unsigned lo = __float_as_uint(v - __uint_as_float(hi)) >> 16;
                            sm.vtr[ml][nl] = hi | lo;
                        }
            }
            __syncthreads();
            {
                const int d     = t >> 1;             // 0..127 (2 heads x 64)
                const int sh    = (t & 1) * 32;       // s-half within pass chunk
                const int headv = (n0 >> 6) + (d >> 6);
                const int dd    = d & 63;
                const int dp    = dd & 7;
                // s-base must be (m0 & 2047); batch lives in the head term
                const size_t basev =
                    ((size_t)(b * NHEADS + headv) * HDIM + dd) * SEQ
                    + ((m0 & 2047) + pass * 64);
#pragma unroll
                for (int k = 0; k < 4; k++) {
                    const int sg = (sh >> 3) + k;     // granule in 64-chunk
                    u16x8 hv, lv;
#pragma unroll
                    for (int e = 0; e < 8; e++) {
                        unsigned u = sm.vtr[sh + k * 8 + e][d];
                        hv[e] = (u16)(u >> 16);
                        lv[e] = (u16)(u & 0xFFFFu);
                    }
                    const int off = ((sg ^ dp) << 3);
                    *(u16x8*)(Vthi + basev + off) = hv;
                    *(u16x8*)(Vtlo + basev + off) = lv;
                }
            }
        }
    }
}

// ---------------------------------------------------------------------------
// FALLBACK fp32 QKV (round-2 kernel) used only if ws_size is too small.
// ---------------------------------------------------------------------------
struct QkvGemmBufs { float As[16][132]; float Bs[16][132]; };
union QkvSmemF { QkvGemmBufs g; unsigned vtr[128][129]; };

__global__ __launch_bounds__(256, 2) void qkv_fp32_kernel(
    const float* __restrict__ X,  const float* __restrict__ W0,
    const float* __restrict__ W1, const float* __restrict__ W2,
    const float* __restrict__ ct, const float* __restrict__ st,
    float* __restrict__ Qo,
    u16* __restrict__ Khi, u16* __restrict__ Klo,
    u16* __restrict__ Vthi, u16* __restrict__ Vtlo)
{
    __shared__ QkvSmemF smem;
    const int t    = threadIdx.x;
    const int proj = blockIdx.z;
    const float* __restrict__ W = (proj == 0) ? W0 : ((proj == 1) ? W1 : W2);
    const int n0 = blockIdx.x * 128;
    const int m0 = blockIdx.y * 128;
    const int tx = t & 15;
    const int ty = t >> 4;
    const int lrow = t >> 1;
    const int lk   = (t & 1) * 8;

    float acc[8][8];
#pragma unroll
    for (int i = 0; i < 8; i++)
#pragma unroll
        for (int j = 0; j < 8; j++) acc[i][j] = 0.f;

    const float* Ap = X + (size_t)(m0 + lrow) * HID + lk;
    const float* Bp = W + (size_t)(n0 + lrow) * HID + lk;

#pragma unroll 1
    for (int kt = 0; kt < HID; kt += 16) {
        float4 a0 = *(const float4*)(Ap + kt);
        float4 a1 = *(const float4*)(Ap + kt + 4);
        float4 b0 = *(const float4*)(Bp + kt);
        float4 b1 = *(const float4*)(Bp + kt + 4);
        __syncthreads();
        {
            const float* af = (const float*)&a0;
            const float* bf = (const float*)&b0;
#pragma unroll
            for (int e = 0; e < 4; e++) { smem.g.As[lk + e][lrow] = af[e]; smem.g.Bs[lk + e][lrow] = bf[e]; }
            af = (const float*)&a1; bf = (const float*)&b1;
#pragma unroll
            for (int e = 0; e < 4; e++) { smem.g.As[lk + 4 + e][lrow] = af[e]; smem.g.Bs[lk + 4 + e][lrow] = bf[e]; }
        }
        __syncthreads();
#pragma unroll
        for (int k = 0; k < 16; k++) {
            float a[8], bb[8];
            *(float4*)&a[0]  = *(const float4*)&smem.g.As[k][ty * 4];
            *(float4*)&a[4]  = *(const float4*)&smem.g.As[k][64 + ty * 4];
            *(float4*)&bb[0] = *(const float4*)&smem.g.Bs[k][tx * 4];
            *(float4*)&bb[4] = *(const float4*)&smem.g.Bs[k][64 + tx * 4];
#pragma unroll
            for (int i = 0; i < 8; i++)
#pragma unroll
                for (int j = 0; j < 8; j++)
                    acc[i][j] = fmaf(a[i], bb[j], acc[i][j]);
        }
    }

    const int dh0   = tx * 4;
    const float sgn = (tx < 8) ? -1.f : 1.f;

    if (proj < 2) {
#pragma unroll
        for (int i = 0; i < 8; i++) {
            const int gr = m0 + ty * 4 + (i & 3) + 64 * (i >> 2);
            const int b  = gr >> 11;
            const int s  = gr & 2047;
            float vals[8];
            float4 c4 = *(const float4*)(ct + s * HDIM + dh0);
            float4 s4 = *(const float4*)(st + s * HDIM + dh0);
            const float* cf = (const float*)&c4;
            const float* sf = (const float*)&s4;
#pragma unroll
            for (int j = 0; j < 8; j++) {
                float av = acc[i][j];
                float pr = __shfl_xor(av, 8);
                vals[j] = av * cf[j & 3] + sgn * pr * sf[j & 3];
            }
#pragma unroll
            for (int jh = 0; jh < 2; jh++) {
                const int head = (n0 >> 6) + jh;
                const size_t rowbase = (((size_t)(b * NHEADS + head) * SEQ + s) * HDIM);
                if (proj == 0) {
                    *(float4*)(Qo + rowbase + dh0) =
                        make_float4(vals[jh*4+0], vals[jh*4+1], vals[jh*4+2], vals[jh*4+3]);
                } else {
                    const int g   = tx >> 1;
                    const int off = (((g ^ (s & 7)) << 3)) + (tx & 1) * 4;
                    ushort4 h4, l4;
                    u16* hp = (u16*)&h4; u16* lp = (u16*)&l4;
#pragma unroll
                    for (int e = 0; e < 4; e++) split1(vals[jh*4+e], hp[e], lp[e]);
                    *(ushort4*)(Khi + rowbase + off) = h4;
                    *(ushort4*)(Klo + rowbase + off) = l4;
                }
            }
        }
    } else {
        __syncthreads();
#pragma unroll
        for (int i = 0; i < 8; i++)
#pragma unroll
            for (int j = 0; j < 8; j++) {
                const int srow = ty * 4 + (i & 3) + 64 * (i >> 2);
                const int ncol = tx * 4 + (j & 3) + 64 * (j >> 2);
                float v = acc[i][j];
                unsigned u  = __float_as_uint(v);
                unsigned hi = u & 0xFFFF0000u;
                unsigned lob = __float_as_uint(v - __uint_as_float(hi)) >> 16;
                smem.vtr[srow][ncol] = hi | lob;
            }
        __syncthreads();
        {
            const int r     = t >> 1;
            const int head  = (n0 >> 6) + (r >> 6);
            const int d     = r & 63;
            const int chunk = (t & 1) * 64;
            const int gr    = m0 + chunk;
            const int b     = gr >> 11;
            const int s0    = gr & 2047;
            const size_t rowbase = ((size_t)(b * NHEADS + head) * HDIM + d) * SEQ + s0;
#pragma unroll
            for (int sg = 0; sg < 8; sg++) {
                u16x8 hv, lv;
#pragma unroll
                for (int e = 0; e < 8; e++) {
                    unsigned u = smem.vtr[chunk + sg * 8 + e][r];
                    hv[e] = (u16)(u >> 16);
                    lv[e] = (u16)(u & 0xFFFFu);
                }
                const int off = ((sg ^ (d & 7)) << 3);
                *(u16x8*)(Vthi + rowbase + off) = hv;
                *(u16x8*)(Vtlo + rowbase + off) = lv;
            }
        }
    }
}

// ---------------------------------------------------------------------------
// Flash-style attention on MFMA; staging now via global_load_lds (m97-style).
// ---------------------------------------------------------------------------
__global__ __launch_bounds__(256, 2) void attn_kernel(
    const float* __restrict__ Q,
    const u16* __restrict__ Khi, const u16* __restrict__ Klo,
    const u16* __restrict__ Vthi, const u16* __restrict__ Vtlo,
    float* __restrict__ OUT)
{
    __shared__ u16 KhiS[4096], KloS[4096], VhiS[4096], VloS[4096];
    __shared__ float PS[4][32][68];

    const int t    = threadIdx.x;
    const int lane = t & 63;
    const int w    = t >> 6;
    const int lx   = lane & 15;
    const int quad = lane >> 4;

    const int q0 = blockIdx.x * 128;
    const int h  = blockIdx.y;
    const int b  = blockIdx.z;
    const size_t base = ((size_t)(b * NHEADS + h)) * SEQ * HDIM;
    const float* Qp = Q + base;
    const u16* KhiB = Khi + base;
    const u16* KloB = Klo + base;
    const u16* VhiB = Vthi + base;
    const u16* VloB = Vtlo + base;

    bf16x8 qhi[2][2], qlo[2][2];
#pragma unroll
    for (int a = 0; a < 2; a++)
#pragma unroll
        for (int ks = 0; ks < 2; ks++) {
            const float* src = Qp + (size_t)(q0 + w * 32 + a * 16 + lx) * HDIM + ks * 32 + quad * 8;
            float xf[8];
            *(float4*)&xf[0] = *(const float4*)src;
            *(float4*)&xf[4] = *(const float4*)(src + 4);
            split8(xf, qhi[a][ks], qlo[a][ks]);
        }

    f32x4 O[2][4];
    float l_part[2][4];
#pragma unroll
    for (int a = 0; a < 2; a++)
#pragma unroll
        for (int dt = 0; dt < 4; dt++) O[a][dt] = (f32x4){0.f,0.f,0.f,0.f};
#pragma unroll
    for (int a = 0; a < 2; a++)
#pragma unroll
        for (int r = 0; r < 4; r++) l_part[a][r] = 0.f;

    // staging addresses: K flat (rows contiguous), V rows strided by SEQ
    const u16* gK0v = KhiB + 8 * t;               // + kt*64
    const u16* gK1v = KloB + 8 * t;
    const u16* gV0v = VhiB + (size_t)(t >> 3) * SEQ + (t & 7) * 8;   // + kt
    const u16* gV1v = VloB + (size_t)(t >> 3) * SEQ + (t & 7) * 8;
    u16* lKh = KhiS + 8 * t;
    u16* lKl = KloS + 8 * t;
    u16* lVh = VhiS + 8 * t;
    u16* lVl = VloS + 8 * t;

#pragma unroll 1
    for (int kt = 0; kt < SEQ; kt += 64) {
        __syncthreads();                          // prev tile reads done
        GLDS(gK0v + (size_t)kt * HDIM,        lKh);
        GLDS(gK0v + (size_t)kt * HDIM + 2048, lKh + 2048);
        GLDS(gK1v + (size_t)kt * HDIM,        lKl);
        GLDS(gK1v + (size_t)kt * HDIM + 2048, lKl + 2048);
        GLDS(gV0v + kt,                        lVh);
        GLDS(gV0v + kt + (size_t)32 * SEQ,     lVh + 2048);
        GLDS(gV1v + kt,                        lVl);
        GLDS(gV1v + kt + (size_t)32 * SEQ,     lVl + 2048);
        __syncthreads();                          // vmcnt drained

#pragma unroll
        for (int a = 0; a < 2; a++) {
#pragma unroll
            for (int c = 0; c < 4; c++) {
                f32x4 acc = (f32x4){0.f,0.f,0.f,0.f};
                const int key = c * 16 + lx;
#pragma unroll
                for (int ks = 0; ks < 2; ks++) {
                    const int doct = ks * 4 + quad;
                    const int off  = key * 64 + ((doct ^ (key & 7)) << 3);
                    bf16x8 kh = *(const bf16x8*)(KhiS + off);
                    bf16x8 kl = *(const bf16x8*)(KloS + off);
                    acc = __builtin_amdgcn_mfma_f32_16x16x32_bf16(qhi[a][ks], kh, acc, 0, 0, 0);
                    acc = __builtin_amdgcn_mfma_f32_16x16x32_bf16(qlo[a][ks], kh, acc, 0, 0, 0);
                    acc = __builtin_amdgcn_mfma_f32_16x16x32_bf16(qhi[a][ks], kl, acc, 0, 0, 0);
                }
#pragma unroll
                for (int r = 0; r < 4; r++) {
                    float p = exp2f(acc[r] * 0.18033688011112042f);
                    l_part[a][r] += p;
                    PS[w][a * 16 + quad * 4 + r][c * 16 + lx] = p;
                }
            }
        }

#pragma unroll
        for (int a = 0; a < 2; a++) {
#pragma unroll
            for (int ks2 = 0; ks2 < 2; ks2++) {
                const float* ps = &PS[w][a * 16 + lx][ks2 * 32 + quad * 8];
                float pf[8];
                *(float4*)&pf[0] = *(const float4*)ps;
                *(float4*)&pf[4] = *(const float4*)(ps + 4);
                bf16x8 phi, plo;
                split8(pf, phi, plo);
#pragma unroll
                for (int dt = 0; dt < 4; dt++) {
                    const int d    = dt * 16 + lx;
                    const int koct = ks2 * 4 + quad;
                    const int off  = d * 64 + ((koct ^ (d & 7)) << 3);
                    bf16x8 vh = *(const bf16x8*)(VhiS + off);
                    bf16x8 vl = *(const bf16x8*)(VloS + off);
                    O[a][dt] = __builtin_amdgcn_mfma_f32_16x16x32_bf16(phi, vh, O[a][dt], 0, 0, 0);
                    O[a][dt] = __builtin_amdgcn_mfma_f32_16x16x32_bf16(plo, vh, O[a][dt], 0, 0, 0);
                    O[a][dt] = __builtin_amdgcn_mfma_f32_16x16x32_bf16(phi, vl, O[a][dt], 0, 0, 0);
                }
            }
        }
    }

    float linv[2][4];
#pragma unroll
    for (int a = 0; a < 2; a++)
#pragma unroll
        for (int r = 0; r < 4; r++) {
            float l = l_part[a][r];
            l += __shfl_xor(l, 1);
            l += __shfl_xor(l, 2);
            l += __shfl_xor(l, 4);
            l += __shfl_xor(l, 8);
            linv[a][r] = 1.f / l;
        }

    float* Po = &PS[0][0][0];
#pragma unroll
    for (int a = 0; a < 2; a++)
#pragma unroll
        for (int dt = 0; dt < 4; dt++)
#pragma unroll
            for (int r = 0; r < 4; r++)
                Po[(size_t)(w * 32 + a * 16 + quad * 4 + r) * 68 + dt * 16 + lx] =
                    O[a][dt][r] * linv[a][r];
    __syncthreads();
    {
        const int q    = t >> 1;
        const int half = t & 1;
        const float* prow = Po + (size_t)q * 68 + half * 32;
        float* dst = OUT + ((size_t)(b * SEQ + q0 + q)) * HID + h * HDIM + half * 32;
#pragma unroll
        for (int e = 0; e < 8; e++)
            ((float4*)dst)[e] = ((const float4*)prow)[e];
    }
}

// ---------------------------------------------------------------------------
extern "C" void kernel_launch(void* const* d_in, const int* in_sizes, int n_in,
                              void* d_out, int out_size, void* d_ws, size_t ws_size,
                              hipStream_t stream)
{
    const float* X  = (const float*)d_in[0];
    const float* Wq = (const float*)d_in[1];
    const float* Wk = (const float*)d_in[2];
    const float* Wv = (const float*)d_in[3];
    float* out = (float*)d_out;

    const size_t qkv_elems = (size_t)BATCH * NHEADS * SEQ * HDIM;  // 4,194,304
    char* wsb = (char*)d_ws;
    float* Qb   = (float*)wsb;                                   // 16 MB
    u16*  Khi   = (u16*)(Qb + qkv_elems);                        // 8 MB
    u16*  Klo   = Khi + qkv_elems;                               // 8 MB
    u16*  Vthi  = Klo + qkv_elems;                               // 8 MB
    u16*  Vtlo  = Vthi + qkv_elems;                              // 8 MB
    float* ct   = (float*)(Vtlo + qkv_elems);                    // 0.5 MB
    float* st   = ct + (size_t)SEQ * HDIM;                       // 0.5 MB  (=49 MB)
    u16*  Xhi   = (u16*)(st + (size_t)SEQ * HDIM);               // 8 MB
    u16*  Xlo   = Xhi + (size_t)NX;                              // 8 MB
    u16*  Whi   = Xlo + (size_t)NX;                              // 6 MB
    u16*  Wlo   = Whi + 3 * (size_t)NW;                          // 6 MB  (=77 MB)
    const size_t need = (size_t)((char*)(Wlo + 3 * (size_t)NW) - wsb);

    rope_tables_kernel<<<(SEQ * HDIM + 255) / 256, 256, 0, stream>>>(ct, st);

    if (ws_size >= need) {
        const long tot = (long)NX + 3L * NW;
        split_kernel<<<(int)((tot / 4 + 255) / 256), 256, 0, stream>>>(
            X, Wq, Wk, Wv, Xhi, Xlo, Whi, Wlo);
        qkv_mfma_kernel<<<dim3(HID / 128, (BATCH * SEQ) / 128, 3), 256, 0, stream>>>(
            Xhi, Xlo, Whi, Wlo, ct, st, Qb, Khi, Klo, Vthi, Vtlo);
    } else {
        qkv_fp32_kernel<<<dim3(HID / 128, (BATCH * SEQ) / 128, 3), 256, 0, stream>>>(
            X, Wq, Wk, Wv, ct, st, Qb, Khi, Klo, Vthi, Vtlo);
    }

    attn_kernel<<<dim3(SEQ / 128, NHEADS, BATCH), 256, 0, stream>>>(
        Qb, Khi, Klo, Vthi, Vtlo, out);
}

// Round 6
// 341.298 us; speedup vs baseline: 1.1232x; 1.1232x over previous
//
#include <hip/hip_runtime.h>
#include <math.h>

#define NHEADS 16
#define HDIM   64
#define HID    1024
#define BATCH  2
#define SEQ    2048

typedef unsigned short u16;
typedef __attribute__((ext_vector_type(8))) short  bf16x8;   // 8 bf16 = 4 VGPR
typedef __attribute__((ext_vector_type(8))) unsigned short u16x8;
typedef __attribute__((ext_vector_type(4))) float  f32x4;

// truncation-based fp32 -> bf16(hi) + bf16(lo) split (error ~2^-16 rel)
__device__ __forceinline__ void split8(const float* xf, bf16x8& hi, bf16x8& lo) {
#pragma unroll
    for (int j = 0; j < 8; j++) {
        unsigned u = __float_as_uint(xf[j]);
        hi[j] = (short)(u >> 16);
        float hf = __uint_as_float(u & 0xFFFF0000u);
        lo[j] = (short)(__float_as_uint(xf[j] - hf) >> 16);
    }
}
__device__ __forceinline__ void split1(float v, u16& h, u16& l) {
    unsigned u = __float_as_uint(v);
    h = (u16)(u >> 16);
    l = (u16)(__float_as_uint(v - __uint_as_float(u & 0xFFFF0000u)) >> 16);
}

// ---------------------------------------------------------------------------
// RoPE tables
// ---------------------------------------------------------------------------
__global__ void rope_tables_kernel(float* __restrict__ ct, float* __restrict__ st) {
    int idx = blockIdx.x * 256 + threadIdx.x;
    if (idx >= SEQ * HDIM) return;
    int s  = idx >> 6;
    int dh = idx & 63;
    int i  = dh & 31;
    float inv = exp2f(-(float)i * (13.28771237954945f / 32.0f));  // log2(10000)/32
    float fr  = (float)s * inv;
    ct[idx] = cosf(fr);
    st[idx] = sinf(fr);
}

// ---------------------------------------------------------------------------
// Pre-pass: split X [4096][1024] and W0/1/2 [1024][1024] fp32 -> bf16 hi/lo
// ---------------------------------------------------------------------------
#define NX (BATCH*SEQ*HID)       // 4194304
#define NW (HID*HID)             // 1048576
__global__ void split_kernel(const float* __restrict__ X,
                             const float* __restrict__ W0,
                             const float* __restrict__ W1,
                             const float* __restrict__ W2,
                             u16* __restrict__ Xhi, u16* __restrict__ Xlo,
                             u16* __restrict__ Whi, u16* __restrict__ Wlo)
{
    long idx = ((long)blockIdx.x * 256 + threadIdx.x) * 4;
    if (idx >= (long)NX + 3L * NW) return;
    const float* src; u16* dh; u16* dl; long off;
    if (idx < NX) { src = X; dh = Xhi; dl = Xlo; off = idx; }
    else {
        long r = idx - NX;
        int wi = (int)(r >> 20);
        off = r & (NW - 1);
        src = (wi == 0) ? W0 : ((wi == 1) ? W1 : W2);
        dh = Whi + (size_t)wi * NW;
        dl = Wlo + (size_t)wi * NW;
    }
    float4 v = *(const float4*)(src + off);
    const float* vf = (const float*)&v;
    ushort4 h4, l4;
    u16* hp = (u16*)&h4; u16* lp = (u16*)&l4;
#pragma unroll
    for (int e = 0; e < 4; e++) split1(vf[e], hp[e], lp[e]);
    *(ushort4*)(dh + off) = h4;
    *(ushort4*)(dl + off) = l4;
}

// ---------------------------------------------------------------------------
// MFMA QKV GEMM: C = X @ W^T via split-bf16 3-term emulation.
// R4 staging (manual ds_write_b128, SP=40 pitch: b128 frag reads cover all
// 32 banks per half-wave -> packed) + software-pipelined prefetch rotation.
// C/D mapping (verified R2): m = i*16 + quad*4 + reg, n = j*16 + (lane&15).
// proj 0: Q fp32 [B][NH][S][D] (RoPE)   proj 1: K bf16 hi/lo perm'd (RoPE)
// proj 2: V bf16 hi/lo transposed [B][NH][D][perm(S)] via 2-pass LDS.
// ---------------------------------------------------------------------------
#define SP 40
union QkvSmem {
    struct { u16 A[2][128 * SP]; u16 B[2][128 * SP]; } s;   // 40 KB staging
    unsigned vtr[64][129];                                   // 33 KB transpose buf
};

__global__ __launch_bounds__(256, 3) void qkv_mfma_kernel(
    const u16* __restrict__ Xhi, const u16* __restrict__ Xlo,
    const u16* __restrict__ Whi, const u16* __restrict__ Wlo,
    const float* __restrict__ ct, const float* __restrict__ st,
    float* __restrict__ Qo,
    u16* __restrict__ Khi, u16* __restrict__ Klo,
    u16* __restrict__ Vthi, u16* __restrict__ Vtlo)
{
    __shared__ QkvSmem sm;

    const int t    = threadIdx.x;
    const int lane = t & 63;
    const int w    = t >> 6;
    const int lx   = lane & 15;
    const int quad = lane >> 4;
    const int proj = blockIdx.z;
    const int n0   = blockIdx.x * 128;
    const int m0   = blockIdx.y * 128;

    const u16* __restrict__ Wph = Whi + (size_t)proj * NW;
    const u16* __restrict__ Wpl = Wlo + (size_t)proj * NW;

    // staging: thread t covers rows r0 and r0+64, 16B chunk (t&3) of the 64B row
    const int r0 = t >> 2;
    const int c0 = (t & 3) * 8;   // u16 offset in 32-col logical row

    const u16* gAh0 = Xhi + (size_t)(m0 + r0) * HID + c0;
    const u16* gAh1 = gAh0 + (size_t)64 * HID;
    const u16* gAl0 = Xlo + (size_t)(m0 + r0) * HID + c0;
    const u16* gAl1 = gAl0 + (size_t)64 * HID;
    const u16* gBh0 = Wph + (size_t)(n0 + r0) * HID + c0;
    const u16* gBh1 = gBh0 + (size_t)64 * HID;
    const u16* gBl0 = Wpl + (size_t)(n0 + r0) * HID + c0;
    const u16* gBl1 = gBl0 + (size_t)64 * HID;

    f32x4 acc[4][4];
#pragma unroll
    for (int i = 0; i < 4; i++)
#pragma unroll
        for (int j = 0; j < 4; j++) acc[i][j] = (f32x4){0.f, 0.f, 0.f, 0.f};

    const int am = (w & 1) * 64;
    const int bn = (w >> 1) * 64;

    // ---- prefetch tile 0 ----
    uint4 ah0 = *(const uint4*)(gAh0);
    uint4 ah1 = *(const uint4*)(gAh1);
    uint4 al0 = *(const uint4*)(gAl0);
    uint4 al1 = *(const uint4*)(gAl1);
    uint4 bh0 = *(const uint4*)(gBh0);
    uint4 bh1 = *(const uint4*)(gBh1);
    uint4 bl0 = *(const uint4*)(gBl0);
    uint4 bl1 = *(const uint4*)(gBl1);

#pragma unroll 1
    for (int kt = 0; kt < HID; kt += 32) {
        __syncthreads();                 // prev tile's frag reads done
        *(uint4*)&sm.s.A[0][r0 * SP + c0]        = ah0;
        *(uint4*)&sm.s.A[0][(r0 + 64) * SP + c0] = ah1;
        *(uint4*)&sm.s.A[1][r0 * SP + c0]        = al0;
        *(uint4*)&sm.s.A[1][(r0 + 64) * SP + c0] = al1;
        *(uint4*)&sm.s.B[0][r0 * SP + c0]        = bh0;
        *(uint4*)&sm.s.B[0][(r0 + 64) * SP + c0] = bh1;
        *(uint4*)&sm.s.B[1][r0 * SP + c0]        = bl0;
        *(uint4*)&sm.s.B[1][(r0 + 64) * SP + c0] = bl1;
        __syncthreads();

        // ---- prefetch next tile (issue before compute; used next iter) ----
        const int kn = (kt + 32 < HID) ? kt + 32 : 0;   // last-iter loads unused
        ah0 = *(const uint4*)(gAh0 + kn);
        ah1 = *(const uint4*)(gAh1 + kn);
        al0 = *(const uint4*)(gAl0 + kn);
        al1 = *(const uint4*)(gAl1 + kn);
        bh0 = *(const uint4*)(gBh0 + kn);
        bh1 = *(const uint4*)(gBh1 + kn);
        bl0 = *(const uint4*)(gBl0 + kn);
        bl1 = *(const uint4*)(gBl1 + kn);

        bf16x8 ah[4], al[4];
#pragma unroll
        for (int i = 0; i < 4; i++) {
            const int r = am + i * 16 + lx;
            ah[i] = *(const bf16x8*)&sm.s.A[0][r * SP + quad * 8];
            al[i] = *(const bf16x8*)&sm.s.A[1][r * SP + quad * 8];
        }
#pragma unroll
        for (int j = 0; j < 4; j++) {
            const int rn = bn + j * 16 + lx;
            bf16x8 bh = *(const bf16x8*)&sm.s.B[0][rn * SP + quad * 8];
            bf16x8 bl = *(const bf16x8*)&sm.s.B[1][rn * SP + quad * 8];
#pragma unroll
            for (int i = 0; i < 4; i++) {
                acc[i][j] = __builtin_amdgcn_mfma_f32_16x16x32_bf16(ah[i], bh, acc[i][j], 0, 0, 0);
                acc[i][j] = __builtin_amdgcn_mfma_f32_16x16x32_bf16(al[i], bh, acc[i][j], 0, 0, 0);
                acc[i][j] = __builtin_amdgcn_mfma_f32_16x16x32_bf16(ah[i], bl, acc[i][j], 0, 0, 0);
            }
        }
    }

    // ---- epilogue ----
    const int b      = m0 >> 11;                 // batch (tiles don't straddle)
    const int head   = (n0 >> 6) + (w >> 1);     // wave's n-half = one head
    const int m_base = m0 + am;

    if (proj < 2) {
        // RoPE in registers: partner dh^32 lives in acc[i][j^2], same lane.
#pragma unroll
        for (int i = 0; i < 4; i++) {
#pragma unroll
            for (int r = 0; r < 4; r++) {
                const int s = (m_base + i * 16 + quad * 4 + r) & 2047;
                const float* ctr = ct + s * HDIM;
                const float* str = st + s * HDIM;
                float nv[4];
#pragma unroll
                for (int j = 0; j < 4; j++) {
                    const int dh = j * 16 + lx;
                    const float c  = ctr[dh];
                    const float sn = str[dh];
                    const float x  = acc[i][j][r];
                    const float p  = acc[i][j ^ 2][r];
                    nv[j] = (j < 2) ? (x * c - p * sn) : (x * c + p * sn);
                }
#pragma unroll
                for (int j = 0; j < 4; j++) acc[i][j][r] = nv[j];
            }
        }
    }

    if (proj == 0) {
        const size_t rowb = (size_t)(b * NHEADS + head) * SEQ;
#pragma unroll
        for (int i = 0; i < 4; i++)
#pragma unroll
            for (int r = 0; r < 4; r++) {
                const int s = (m_base + i * 16 + quad * 4 + r) & 2047;
                float* dst = Qo + (rowb + s) * HDIM;
#pragma unroll
                for (int j = 0; j < 4; j++) dst[j * 16 + lx] = acc[i][j][r];
            }
    } else if (proj == 1) {
        const size_t rowb = (size_t)(b * NHEADS + head) * SEQ;
#pragma unroll
        for (int i = 0; i < 4; i++)
#pragma unroll
            for (int r = 0; r < 4; r++) {
                const int s  = (m_base + i * 16 + quad * 4 + r) & 2047;
                const int sp = s & 7;
                u16* dsth = Khi + (rowb + s) * HDIM;
                u16* dstl = Klo + (rowb + s) * HDIM;
#pragma unroll
                for (int j = 0; j < 4; j++) {
                    const int dh  = j * 16 + lx;
                    const int off = (((dh >> 3) ^ sp) << 3) + (dh & 7);
                    u16 h, l;
                    split1(acc[i][j][r], h, l);
                    dsth[off] = h;
                    dstl[off] = l;
                }
            }
    } else {
        // V: two-pass LDS transpose -> [B][NH][D][perm(S)]
#pragma unroll 1
        for (int pass = 0; pass < 2; pass++) {
            __syncthreads();   // staging reads done (pass 0) / prev pass reads done
            if ((w & 1) == pass) {
#pragma unroll
                for (int i = 0; i < 4; i++)
#pragma unroll
                    for (int j = 0; j < 4; j++)
#pragma unroll
                        for (int r = 0; r < 4; r++) {
                            const int ml = i * 16 + quad * 4 + r;     // 0..63 in pass
                            const int nl = bn + j * 16 + lx;          // 0..127
                            const float v = acc[i][j][r];
                            unsigned u  = __float_as_uint(v);
                            unsigned hi = u & 0xFFFF0000u;
                            unsigned lo = __float_as_uint(v - __uint_as_float(hi)) >> 16;
                            sm.vtr[ml][nl] = hi | lo;
                        }
            }
            __syncthreads();
            {
                const int d     = t >> 1;             // 0..127 (2 heads x 64)
                const int sh    = (t & 1) * 32;       // s-half within pass chunk
                const int headv = (n0 >> 6) + (d >> 6);
                const int dd    = d & 63;
                const int dp    = dd & 7;
                // s-base must be (m0 & 2047); batch lives in the head term
                const size_t basev =
                    ((size_t)(b * NHEADS + headv) * HDIM + dd) * SEQ
                    + ((m0 & 2047) + pass * 64);
#pragma unroll
                for (int k = 0; k < 4; k++) {
                    const int sg = (sh >> 3) + k;     // granule in 64-chunk
                    u16x8 hv, lv;
#pragma unroll
                    for (int e = 0; e < 8; e++) {
                        unsigned u = sm.vtr[sh + k * 8 + e][d];
                        hv[e] = (u16)(u >> 16);
                        lv[e] = (u16)(u & 0xFFFFu);
                    }
                    const int off = ((sg ^ dp) << 3);
                    *(u16x8*)(Vthi + basev + off) = hv;
                    *(u16x8*)(Vtlo + basev + off) = lv;
                }
            }
        }
    }
}

// ---------------------------------------------------------------------------
// FALLBACK fp32 QKV (round-2 kernel) used only if ws_size is too small.
// ---------------------------------------------------------------------------
struct QkvGemmBufs { float As[16][132]; float Bs[16][132]; };
union QkvSmemF { QkvGemmBufs g; unsigned vtr[128][129]; };

__global__ __launch_bounds__(256, 2) void qkv_fp32_kernel(
    const float* __restrict__ X,  const float* __restrict__ W0,
    const float* __restrict__ W1, const float* __restrict__ W2,
    const float* __restrict__ ct, const float* __restrict__ st,
    float* __restrict__ Qo,
    u16* __restrict__ Khi, u16* __restrict__ Klo,
    u16* __restrict__ Vthi, u16* __restrict__ Vtlo)
{
    __shared__ QkvSmemF smem;
    const int t    = threadIdx.x;
    const int proj = blockIdx.z;
    const float* __restrict__ W = (proj == 0) ? W0 : ((proj == 1) ? W1 : W2);
    const int n0 = blockIdx.x * 128;
    const int m0 = blockIdx.y * 128;
    const int tx = t & 15;
    const int ty = t >> 4;
    const int lrow = t >> 1;
    const int lk   = (t & 1) * 8;

    float acc[8][8];
#pragma unroll
    for (int i = 0; i < 8; i++)
#pragma unroll
        for (int j = 0; j < 8; j++) acc[i][j] = 0.f;

    const float* Ap = X + (size_t)(m0 + lrow) * HID + lk;
    const float* Bp = W + (size_t)(n0 + lrow) * HID + lk;

#pragma unroll 1
    for (int kt = 0; kt < HID; kt += 16) {
        float4 a0 = *(const float4*)(Ap + kt);
        float4 a1 = *(const float4*)(Ap + kt + 4);
        float4 b0 = *(const float4*)(Bp + kt);
        float4 b1 = *(const float4*)(Bp + kt + 4);
        __syncthreads();
        {
            const float* af = (const float*)&a0;
            const float* bf = (const float*)&b0;
#pragma unroll
            for (int e = 0; e < 4; e++) { smem.g.As[lk + e][lrow] = af[e]; smem.g.Bs[lk + e][lrow] = bf[e]; }
            af = (const float*)&a1; bf = (const float*)&b1;
#pragma unroll
            for (int e = 0; e < 4; e++) { smem.g.As[lk + 4 + e][lrow] = af[e]; smem.g.Bs[lk + 4 + e][lrow] = bf[e]; }
        }
        __syncthreads();
#pragma unroll
        for (int k = 0; k < 16; k++) {
            float a[8], bb[8];
            *(float4*)&a[0]  = *(const float4*)&smem.g.As[k][ty * 4];
            *(float4*)&a[4]  = *(const float4*)&smem.g.As[k][64 + ty * 4];
            *(float4*)&bb[0] = *(const float4*)&smem.g.Bs[k][tx * 4];
            *(float4*)&bb[4] = *(const float4*)&smem.g.Bs[k][64 + tx * 4];
#pragma unroll
            for (int i = 0; i < 8; i++)
#pragma unroll
                for (int j = 0; j < 8; j++)
                    acc[i][j] = fmaf(a[i], bb[j], acc[i][j]);
        }
    }

    const int dh0   = tx * 4;
    const float sgn = (tx < 8) ? -1.f : 1.f;

    if (proj < 2) {
#pragma unroll
        for (int i = 0; i < 8; i++) {
            const int gr = m0 + ty * 4 + (i & 3) + 64 * (i >> 2);
            const int b  = gr >> 11;
            const int s  = gr & 2047;
            float vals[8];
            float4 c4 = *(const float4*)(ct + s * HDIM + dh0);
            float4 s4 = *(const float4*)(st + s * HDIM + dh0);
            const float* cf = (const float*)&c4;
            const float* sf = (const float*)&s4;
#pragma unroll
            for (int j = 0; j < 8; j++) {
                float av = acc[i][j];
                float pr = __shfl_xor(av, 8);
                vals[j] = av * cf[j & 3] + sgn * pr * sf[j & 3];
            }
#pragma unroll
            for (int jh = 0; jh < 2; jh++) {
                const int head = (n0 >> 6) + jh;
                const size_t rowbase = (((size_t)(b * NHEADS + head) * SEQ + s) * HDIM);
                if (proj == 0) {
                    *(float4*)(Qo + rowbase + dh0) =
                        make_float4(vals[jh*4+0], vals[jh*4+1], vals[jh*4+2], vals[jh*4+3]);
                } else {
                    const int g   = tx >> 1;
                    const int off = (((g ^ (s & 7)) << 3)) + (tx & 1) * 4;
                    ushort4 h4, l4;
                    u16* hp = (u16*)&h4; u16* lp = (u16*)&l4;
#pragma unroll
                    for (int e = 0; e < 4; e++) split1(vals[jh*4+e], hp[e], lp[e]);
                    *(ushort4*)(Khi + rowbase + off) = h4;
                    *(ushort4*)(Klo + rowbase + off) = l4;
                }
            }
        }
    } else {
        __syncthreads();
#pragma unroll
        for (int i = 0; i < 8; i++)
#pragma unroll
            for (int j = 0; j < 8; j++) {
                const int srow = ty * 4 + (i & 3) + 64 * (i >> 2);
                const int ncol = tx * 4 + (j & 3) + 64 * (j >> 2);
                float v = acc[i][j];
                unsigned u  = __float_as_uint(v);
                unsigned hi = u & 0xFFFF0000u;
                unsigned lob = __float_as_uint(v - __uint_as_float(hi)) >> 16;
                smem.vtr[srow][ncol] = hi | lob;
            }
        __syncthreads();
        {
            const int r     = t >> 1;
            const int head  = (n0 >> 6) + (r >> 6);
            const int d     = r & 63;
            const int chunk = (t & 1) * 64;
            const int gr    = m0 + chunk;
            const int b     = gr >> 11;
            const int s0    = gr & 2047;
            const size_t rowbase = ((size_t)(b * NHEADS + head) * HDIM + d) * SEQ + s0;
#pragma unroll
            for (int sg = 0; sg < 8; sg++) {
                u16x8 hv, lv;
#pragma unroll
                for (int e = 0; e < 8; e++) {
                    unsigned u = smem.vtr[chunk + sg * 8 + e][r];
                    hv[e] = (u16)(u >> 16);
                    lv[e] = (u16)(u & 0xFFFFu);
                }
                const int off = ((sg ^ (d & 7)) << 3);
                *(u16x8*)(Vthi + rowbase + off) = hv;
                *(u16x8*)(Vtlo + rowbase + off) = lv;
            }
        }
    }
}

// ---------------------------------------------------------------------------
// Flash-style attention on MFMA (R2 manual staging + prefetch rotation).
// ---------------------------------------------------------------------------
__global__ __launch_bounds__(256, 2) void attn_kernel(
    const float* __restrict__ Q,
    const u16* __restrict__ Khi, const u16* __restrict__ Klo,
    const u16* __restrict__ Vthi, const u16* __restrict__ Vtlo,
    float* __restrict__ OUT)
{
    __shared__ u16 KhiS[4096], KloS[4096], VhiS[4096], VloS[4096];
    __shared__ float PS[4][32][68];

    const int t    = threadIdx.x;
    const int lane = t & 63;
    const int w    = t >> 6;
    const int lx   = lane & 15;
    const int quad = lane >> 4;

    const int q0 = blockIdx.x * 128;
    const int h  = blockIdx.y;
    const int b  = blockIdx.z;
    const size_t base = ((size_t)(b * NHEADS + h)) * SEQ * HDIM;
    const float* Qp = Q + base;

    bf16x8 qhi[2][2], qlo[2][2];
#pragma unroll
    for (int a = 0; a < 2; a++)
#pragma unroll
        for (int ks = 0; ks < 2; ks++) {
            const float* src = Qp + (size_t)(q0 + w * 32 + a * 16 + lx) * HDIM + ks * 32 + quad * 8;
            float xf[8];
            *(float4*)&xf[0] = *(const float4*)src;
            *(float4*)&xf[4] = *(const float4*)(src + 4);
            split8(xf, qhi[a][ks], qlo[a][ks]);
        }

    f32x4 O[2][4];
    float l_part[2][4];
#pragma unroll
    for (int a = 0; a < 2; a++)
#pragma unroll
        for (int dt = 0; dt < 4; dt++) O[a][dt] = (f32x4){0.f,0.f,0.f,0.f};
#pragma unroll
    for (int a = 0; a < 2; a++)
#pragma unroll
        for (int r = 0; r < 4; r++) l_part[a][r] = 0.f;

    // per-thread staging addresses
    const int so   = t * 8;                        // K: flat u16 offset
    const int vrow = t >> 2;                       // V: d-row
    const int vcol = (t & 3) * 16;                 // V: s-col (u16)
    const u16* pKh = Khi + base + so;              // + kt*HDIM
    const u16* pKl = Klo + base + so;
    const u16* pVh = Vthi + base + (size_t)vrow * SEQ + vcol;  // + kt
    const u16* pVl = Vtlo + base + (size_t)vrow * SEQ + vcol;
    u16* dVh = VhiS + vrow * 64 + vcol;
    u16* dVl = VloS + vrow * 64 + vcol;

    // ---- prefetch tile 0 ----
    uint4 kh0 = *(const uint4*)(pKh);
    uint4 kh1 = *(const uint4*)(pKh + 2048);
    uint4 kl0 = *(const uint4*)(pKl);
    uint4 kl1 = *(const uint4*)(pKl + 2048);
    uint4 vh0 = *(const uint4*)(pVh);
    uint4 vh1 = *(const uint4*)(pVh + 8);
    uint4 vl0 = *(const uint4*)(pVl);
    uint4 vl1 = *(const uint4*)(pVl + 8);

#pragma unroll 1
    for (int kt = 0; kt < SEQ; kt += 64) {
        __syncthreads();                           // prev tile reads done
        *(uint4*)(KhiS + so) = kh0;
        *(uint4*)(KhiS + 2048 + so) = kh1;
        *(uint4*)(KloS + so) = kl0;
        *(uint4*)(KloS + 2048 + so) = kl1;
        *(uint4*)dVh       = vh0;
        *(uint4*)(dVh + 8) = vh1;
        *(uint4*)dVl       = vl0;
        *(uint4*)(dVl + 8) = vl1;
        __syncthreads();

        // ---- prefetch next tile (used next iteration) ----
        const int kn = (kt + 64 < SEQ) ? kt + 64 : 0;
        kh0 = *(const uint4*)(pKh + (size_t)kn * HDIM);
        kh1 = *(const uint4*)(pKh + (size_t)kn * HDIM + 2048);
        kl0 = *(const uint4*)(pKl + (size_t)kn * HDIM);
        kl1 = *(const uint4*)(pKl + (size_t)kn * HDIM + 2048);
        vh0 = *(const uint4*)(pVh + kn);
        vh1 = *(const uint4*)(pVh + kn + 8);
        vl0 = *(const uint4*)(pVl + kn);
        vl1 = *(const uint4*)(pVl + kn + 8);

#pragma unroll
        for (int a = 0; a < 2; a++) {
#pragma unroll
            for (int c = 0; c < 4; c++) {
                f32x4 acc = (f32x4){0.f,0.f,0.f,0.f};
                const int key = c * 16 + lx;
#pragma unroll
                for (int ks = 0; ks < 2; ks++) {
                    const int doct = ks * 4 + quad;
                    const int off  = key * 64 + ((doct ^ (key & 7)) << 3);
                    bf16x8 kh = *(const bf16x8*)(KhiS + off);
                    bf16x8 kl = *(const bf16x8*)(KloS + off);
                    acc = __builtin_amdgcn_mfma_f32_16x16x32_bf16(qhi[a][ks], kh, acc, 0, 0, 0);
                    acc = __builtin_amdgcn_mfma_f32_16x16x32_bf16(qlo[a][ks], kh, acc, 0, 0, 0);
                    acc = __builtin_amdgcn_mfma_f32_16x16x32_bf16(qhi[a][ks], kl, acc, 0, 0, 0);
                }
#pragma unroll
                for (int r = 0; r < 4; r++) {
                    float p = exp2f(acc[r] * 0.18033688011112042f);
                    l_part[a][r] += p;
                    PS[w][a * 16 + quad * 4 + r][c * 16 + lx] = p;
                }
            }
        }

#pragma unroll
        for (int a = 0; a < 2; a++) {
#pragma unroll
            for (int ks2 = 0; ks2 < 2; ks2++) {
                const float* ps = &PS[w][a * 16 + lx][ks2 * 32 + quad * 8];
                float pf[8];
                *(float4*)&pf[0] = *(const float4*)ps;
                *(float4*)&pf[4] = *(const float4*)(ps + 4);
                bf16x8 phi, plo;
                split8(pf, phi, plo);
#pragma unroll
                for (int dt = 0; dt < 4; dt++) {
                    const int d    = dt * 16 + lx;
                    const int koct = ks2 * 4 + quad;
                    const int off  = d * 64 + ((koct ^ (d & 7)) << 3);
                    bf16x8 vh = *(const bf16x8*)(VhiS + off);
                    bf16x8 vl = *(const bf16x8*)(VloS + off);
                    O[a][dt] = __builtin_amdgcn_mfma_f32_16x16x32_bf16(phi, vh, O[a][dt], 0, 0, 0);
                    O[a][dt] = __builtin_amdgcn_mfma_f32_16x16x32_bf16(plo, vh, O[a][dt], 0, 0, 0);
                    O[a][dt] = __builtin_amdgcn_mfma_f32_16x16x32_bf16(phi, vl, O[a][dt], 0, 0, 0);
                }
            }
        }
    }

    float linv[2][4];
#pragma unroll
    for (int a = 0; a < 2; a++)
#pragma unroll
        for (int r = 0; r < 4; r++) {
            float l = l_part[a][r];
            l += __shfl_xor(l, 1);
            l += __shfl_xor(l, 2);
            l += __shfl_xor(l, 4);
            l += __shfl_xor(l, 8);
            linv[a][r] = 1.f / l;
        }

    float* Po = &PS[0][0][0];
#pragma unroll
    for (int a = 0; a < 2; a++)
#pragma unroll
        for (int dt = 0; dt < 4; dt++)
#pragma unroll
            for (int r = 0; r < 4; r++)
                Po[(size_t)(w * 32 + a * 16 + quad * 4 + r) * 68 + dt * 16 + lx] =
                    O[a][dt][r] * linv[a][r];
    __syncthreads();
    {
        const int q    = t >> 1;
        const int half = t & 1;
        const float* prow = Po + (size_t)q * 68 + half * 32;
        float* dst = OUT + ((size_t)(b * SEQ + q0 + q)) * HID + h * HDIM + half * 32;
#pragma unroll
        for (int e = 0; e < 8; e++)
            ((float4*)dst)[e] = ((const float4*)prow)[e];
    }
}

// ---------------------------------------------------------------------------
extern "C" void kernel_launch(void* const* d_in, const int* in_sizes, int n_in,
                              void* d_out, int out_size, void* d_ws, size_t ws_size,
                              hipStream_t stream)
{
    const float* X  = (const float*)d_in[0];
    const float* Wq = (const float*)d_in[1];
    const float* Wk = (const float*)d_in[2];
    const float* Wv = (const float*)d_in[3];
    float* out = (float*)d_out;

    const size_t qkv_elems = (size_t)BATCH * NHEADS * SEQ * HDIM;  // 4,194,304
    char* wsb = (char*)d_ws;
    float* Qb   = (float*)wsb;                                   // 16 MB
    u16*  Khi   = (u16*)(Qb + qkv_elems);                        // 8 MB
    u16*  Klo   = Khi + qkv_elems;                               // 8 MB
    u16*  Vthi  = Klo + qkv_elems;                               // 8 MB
    u16*  Vtlo  = Vthi + qkv_elems;                              // 8 MB
    float* ct   = (float*)(Vtlo + qkv_elems);                    // 0.5 MB
    float* st   = ct + (size_t)SEQ * HDIM;                       // 0.5 MB  (=49 MB)
    u16*  Xhi   = (u16*)(st + (size_t)SEQ * HDIM);               // 8 MB
    u16*  Xlo   = Xhi + (size_t)NX;                              // 8 MB
    u16*  Whi   = Xlo + (size_t)NX;                              // 6 MB
    u16*  Wlo   = Whi + 3 * (size_t)NW;                          // 6 MB  (=77 MB)
    const size_t need = (size_t)((char*)(Wlo + 3 * (size_t)NW) - wsb);

    rope_tables_kernel<<<(SEQ * HDIM + 255) / 256, 256, 0, stream>>>(ct, st);

    if (ws_size >= need) {
        const long tot = (long)NX + 3L * NW;
        split_kernel<<<(int)((tot / 4 + 255) / 256), 256, 0, stream>>>(
            X, Wq, Wk, Wv, Xhi, Xlo, Whi, Wlo);
        qkv_mfma_kernel<<<dim3(HID / 128, (BATCH * SEQ) / 128, 3), 256, 0, stream>>>(
            Xhi, Xlo, Whi, Wlo, ct, st, Qb, Khi, Klo, Vthi, Vtlo);
    } else {
        qkv_fp32_kernel<<<dim3(HID / 128, (BATCH * SEQ) / 128, 3), 256, 0, stream>>>(
            X, Wq, Wk, Wv, ct, st, Qb, Khi, Klo, Vthi, Vtlo);
    }

    attn_kernel<<<dim3(SEQ / 128, NHEADS, BATCH), 256, 0, stream>>>(
        Qb, Khi, Klo, Vthi, Vtlo, out);
}

// Round 7
// 337.053 us; speedup vs baseline: 1.1374x; 1.0126x over previous
//
#include <hip/hip_runtime.h>
#include <math.h>

#define NHEADS 16
#define HDIM   64
#define HID    1024
#define BATCH  2
#define SEQ    2048
#define NX (BATCH*SEQ*HID)       // 4194304
#define NW (HID*HID)             // 1048576

typedef unsigned short u16;
typedef __attribute__((ext_vector_type(8))) short  bf16x8;   // 8 bf16 = 4 VGPR
typedef __attribute__((ext_vector_type(8))) unsigned short u16x8;
typedef __attribute__((ext_vector_type(4))) float  f32x4;

// ---------------------------------------------------------------------------
// Fragment-tiled layout ("FT"): operand rows r, inner dim k. Subtile =
// 16 rows x 32 k. Element (r,k) lives at
//   ((r>>4)*KB + (k>>5))*512 + ((k>>3)&3)*128 + (r&15)*8 + (k&7)     [u16]
// (KB = k-blocks per row-block row). A wave's MFMA fragment load
// (lane = quad*16+lx -> 16B) is then 64 lanes x 16B CONTIGUOUS: perfectly
// coalesced global_load_dwordx4, no LDS round-trip needed.
// hi / lo planes are separate arrays (keeps lane stride 16B).
// ---------------------------------------------------------------------------

__device__ __forceinline__ void split8(const float* xf, bf16x8& hi, bf16x8& lo) {
#pragma unroll
    for (int j = 0; j < 8; j++) {
        unsigned u = __float_as_uint(xf[j]);
        hi[j] = (short)(u >> 16);
        float hf = __uint_as_float(u & 0xFFFF0000u);
        lo[j] = (short)(__float_as_uint(xf[j] - hf) >> 16);
    }
}
__device__ __forceinline__ void split1(float v, u16& h, u16& l) {
    unsigned u = __float_as_uint(v);
    h = (u16)(u >> 16);
    l = (u16)(__float_as_uint(v - __uint_as_float(u & 0xFFFF0000u)) >> 16);
}

// ---------------------------------------------------------------------------
// RoPE tables
// ---------------------------------------------------------------------------
__global__ void rope_tables_kernel(float* __restrict__ ct, float* __restrict__ st) {
    int idx = blockIdx.x * 256 + threadIdx.x;
    if (idx >= SEQ * HDIM) return;
    int s  = idx >> 6;
    int dh = idx & 63;
    int i  = dh & 31;
    float inv = exp2f(-(float)i * (13.28771237954945f / 32.0f));  // log2(10000)/32
    float fr  = (float)s * inv;
    ct[idx] = cosf(fr);
    st[idx] = sinf(fr);
}

// ---------------------------------------------------------------------------
// Pre-pass: split X and W0/1/2 fp32 -> bf16 hi/lo planes, FRAG-TILED (KB=32).
// ---------------------------------------------------------------------------
__global__ void split_kernel(const float* __restrict__ X,
                             const float* __restrict__ W0,
                             const float* __restrict__ W1,
                             const float* __restrict__ W2,
                             u16* __restrict__ Xhi, u16* __restrict__ Xlo,
                             u16* __restrict__ Whi, u16* __restrict__ Wlo)
{
    long idx = ((long)blockIdx.x * 256 + threadIdx.x) * 4;
    if (idx >= (long)NX + 3L * NW) return;
    const float* src; u16* dh; u16* dl; long off;
    if (idx < NX) { src = X; dh = Xhi; dl = Xlo; off = idx; }
    else {
        long rr = idx - NX;
        int wi = (int)(rr >> 20);
        off = rr & (NW - 1);
        src = (wi == 0) ? W0 : ((wi == 1) ? W1 : W2);
        dh = Whi + (size_t)wi * NW;
        dl = Wlo + (size_t)wi * NW;
    }
    const int r = (int)(off >> 10);
    const int k = (int)(off & 1023);
    // frag-tiled offset (KB=32):
    const size_t fo = ((size_t)(r >> 4) * 32 + (k >> 5)) * 512
                    + (size_t)((k >> 3) & 3) * 128 + (size_t)(r & 15) * 8 + (k & 7);
    float4 v = *(const float4*)(src + off);
    const float* vf = (const float*)&v;
    ushort4 h4, l4;
    u16* hp = (u16*)&h4; u16* lp = (u16*)&l4;
#pragma unroll
    for (int e = 0; e < 4; e++) split1(vf[e], hp[e], lp[e]);
    *(ushort4*)(dh + fo) = h4;
    *(ushort4*)(dl + fo) = l4;
}

// ---------------------------------------------------------------------------
// MFMA QKV GEMM, NO LDS / NO BARRIERS in the K-loop: fragments loaded
// directly from frag-tiled global (L1/L2-hot), register double-buffered.
// 128x128 block, 4 waves x 64x64, split-bf16 3-term emulation.
// Outputs (all frag-tiled, hi/lo planes, per (b,head) base = (b*16+h)*S*D):
//   proj 0: Q (RoPE)  rows=s, k=dh, KB=2
//   proj 1: K (RoPE)  rows=s, k=dh, KB=2
//   proj 2: V^T       rows=d, k=s,  KB=64  (via LDS transpose in epilogue)
// ---------------------------------------------------------------------------
__global__ __launch_bounds__(256, 2) void qkv_mfma_kernel(
    const u16* __restrict__ Xhi, const u16* __restrict__ Xlo,
    const u16* __restrict__ Whi, const u16* __restrict__ Wlo,
    const float* __restrict__ ct, const float* __restrict__ st,
    u16* __restrict__ Qhi, u16* __restrict__ Qlo,
    u16* __restrict__ Khi, u16* __restrict__ Klo,
    u16* __restrict__ Vhi, u16* __restrict__ Vlo)
{
    __shared__ unsigned vtr[64][129];   // proj-2 transpose buffer only

    const int t    = threadIdx.x;
    const int lane = t & 63;
    const int w    = t >> 6;
    const int lx   = lane & 15;
    const int quad = lane >> 4;
    const int proj = blockIdx.z;
    const int n0   = blockIdx.x * 128;
    const int m0   = blockIdx.y * 128;

    const u16* __restrict__ Wph = Whi + (size_t)proj * NW;
    const u16* __restrict__ Wpl = Wlo + (size_t)proj * NW;

    const int am = (w & 1) * 64;
    const int bn = (w >> 1) * 64;
    const int lp = quad * 128 + lx * 8;        // lane part of frag offset

    const u16 *pAh[4], *pAl[4], *pBh[4], *pBl[4];
#pragma unroll
    for (int i = 0; i < 4; i++) {
        const size_t o = ((size_t)(((m0 + am) >> 4) + i) * 32) * 512 + lp;
        pAh[i] = Xhi + o; pAl[i] = Xlo + o;
    }
#pragma unroll
    for (int j = 0; j < 4; j++) {
        const size_t o = ((size_t)(((n0 + bn) >> 4) + j) * 32) * 512 + lp;
        pBh[j] = Wph + o; pBl[j] = Wpl + o;
    }

    f32x4 acc[4][4];
#pragma unroll
    for (int i = 0; i < 4; i++)
#pragma unroll
        for (int j = 0; j < 4; j++) acc[i][j] = (f32x4){0.f, 0.f, 0.f, 0.f};

    // prefetch k-block 0
    bf16x8 cah[4], cal[4], cbh[4], cbl[4];
#pragma unroll
    for (int i = 0; i < 4; i++) { cah[i] = *(const bf16x8*)(pAh[i]); cal[i] = *(const bf16x8*)(pAl[i]); }
#pragma unroll
    for (int j = 0; j < 4; j++) { cbh[j] = *(const bf16x8*)(pBh[j]); cbl[j] = *(const bf16x8*)(pBl[j]); }

#pragma unroll 1
    for (int kt = 0; kt < HID; kt += 32) {
        const int ko = (kt + 32 < HID) ? ((kt + 32) >> 5) * 512 : 0;
        bf16x8 nah[4], nal[4], nbh[4], nbl[4];
#pragma unroll
        for (int i = 0; i < 4; i++) { nah[i] = *(const bf16x8*)(pAh[i] + ko); nal[i] = *(const bf16x8*)(pAl[i] + ko); }
#pragma unroll
        for (int j = 0; j < 4; j++) { nbh[j] = *(const bf16x8*)(pBh[j] + ko); nbl[j] = *(const bf16x8*)(pBl[j] + ko); }

#pragma unroll
        for (int j = 0; j < 4; j++)
#pragma unroll
            for (int i = 0; i < 4; i++) {
                acc[i][j] = __builtin_amdgcn_mfma_f32_16x16x32_bf16(cah[i], cbh[j], acc[i][j], 0, 0, 0);
                acc[i][j] = __builtin_amdgcn_mfma_f32_16x16x32_bf16(cal[i], cbh[j], acc[i][j], 0, 0, 0);
                acc[i][j] = __builtin_amdgcn_mfma_f32_16x16x32_bf16(cah[i], cbl[j], acc[i][j], 0, 0, 0);
            }
#pragma unroll
        for (int i = 0; i < 4; i++) { cah[i] = nah[i]; cal[i] = nal[i]; }
#pragma unroll
        for (int j = 0; j < 4; j++) { cbh[j] = nbh[j]; cbl[j] = nbl[j]; }
    }

    // ---- epilogue ----
    const int b      = m0 >> 11;
    const int head   = (n0 >> 6) + (w >> 1);
    const int m_base = m0 + am;

    if (proj < 2) {
        // RoPE in registers: partner dh^32 = acc[i][j^2], same lane.
#pragma unroll
        for (int i = 0; i < 4; i++) {
#pragma unroll
            for (int r = 0; r < 4; r++) {
                const int s = (m_base + i * 16 + quad * 4 + r) & 2047;
                const float* ctr = ct + s * HDIM;
                const float* str = st + s * HDIM;
                float nv[4];
#pragma unroll
                for (int j = 0; j < 4; j++) {
                    const int dh = j * 16 + lx;
                    const float c  = ctr[dh];
                    const float sn = str[dh];
                    const float x  = acc[i][j][r];
                    const float p  = acc[i][j ^ 2][r];
                    nv[j] = (j < 2) ? (x * c - p * sn) : (x * c + p * sn);
                }
#pragma unroll
                for (int j = 0; j < 4; j++) acc[i][j][r] = nv[j];
            }
        }
        // store Q or K, frag-tiled (rows=s, k=dh, KB=2)
        u16* dh_ = (proj == 0) ? Qhi : Khi;
        u16* dl_ = (proj == 0) ? Qlo : Klo;
        const size_t obase = (size_t)(b * NHEADS + head) * SEQ * HDIM;
#pragma unroll
        for (int i = 0; i < 4; i++)
#pragma unroll
            for (int r = 0; r < 4; r++) {
                const int s   = (m_base + i * 16 + quad * 4 + r) & 2047;
                const int rb  = s >> 4;
                const int lxq = s & 15;
#pragma unroll
                for (int j = 0; j < 4; j++) {
                    const size_t fo = obase + ((size_t)rb * 2 + (j >> 1)) * 512
                                    + (size_t)((j & 1) * 2 + (lx >> 3)) * 128
                                    + (size_t)lxq * 8 + (lx & 7);
                    u16 hh, ll;
                    split1(acc[i][j][r], hh, ll);
                    dh_[fo] = hh;
                    dl_[fo] = ll;
                }
            }
    } else {
        // V: two-pass LDS transpose -> frag-tiled V^T (rows=d, k=s, KB=64)
#pragma unroll 1
        for (int pass = 0; pass < 2; pass++) {
            __syncthreads();
            if ((w & 1) == pass) {
#pragma unroll
                for (int i = 0; i < 4; i++)
#pragma unroll
                    for (int j = 0; j < 4; j++)
#pragma unroll
                        for (int r = 0; r < 4; r++) {
                            const int ml = i * 16 + quad * 4 + r;
                            const int nl = bn + j * 16 + lx;
                            const float v = acc[i][j][r];
                            unsigned u  = __float_as_uint(v);
                            unsigned hi = u & 0xFFFF0000u;
                            unsigned lo = __float_as_uint(v - __uint_as_float(hi)) >> 16;
                            vtr[ml][nl] = hi | lo;
                        }
            }
            __syncthreads();
            {
                const int d      = t >> 1;            // 0..127 (2 heads x 64)
                const int sh     = (t & 1) * 32;
                const int headv  = (n0 >> 6) + (d >> 6);
                const int dd     = d & 63;
                const size_t vbase = (size_t)(b * NHEADS + headv) * SEQ * HDIM;
                const int s0base = (m0 & 2047) + pass * 64 + sh;
#pragma unroll
                for (int k = 0; k < 4; k++) {
                    const int s0 = s0base + k * 8;
                    u16x8 hv, lv;
#pragma unroll
                    for (int e = 0; e < 8; e++) {
                        unsigned u = vtr[sh + k * 8 + e][d];
                        hv[e] = (u16)(u >> 16);
                        lv[e] = (u16)(u & 0xFFFFu);
                    }
                    const size_t fo = vbase + ((size_t)(dd >> 4) * 64 + (s0 >> 5)) * 512
                                    + (size_t)((s0 >> 3) & 3) * 128 + (size_t)(dd & 15) * 8;
                    *(u16x8*)(Vhi + fo) = hv;
                    *(u16x8*)(Vlo + fo) = lv;
                }
            }
        }
    }
}

// ---------------------------------------------------------------------------
// Flash attention, NO LDS for K/V (frag-tiled global loads), NO barriers in
// the tile loop. P round-trips per-wave LDS (wave-internal, lgkmcnt only).
// ---------------------------------------------------------------------------
__global__ __launch_bounds__(256, 2) void attn_kernel(
    const u16* __restrict__ Qhi, const u16* __restrict__ Qlo,
    const u16* __restrict__ Khi, const u16* __restrict__ Klo,
    const u16* __restrict__ Vhi, const u16* __restrict__ Vlo,
    float* __restrict__ OUT)
{
    __shared__ float PS[4][32][68];

    const int t    = threadIdx.x;
    const int lane = t & 63;
    const int w    = t >> 6;
    const int lx   = lane & 15;
    const int quad = lane >> 4;

    const int q0 = blockIdx.x * 128;
    const int h  = blockIdx.y;
    const int b  = blockIdx.z;
    const size_t base = (size_t)(b * NHEADS + h) * SEQ * HDIM;
    const int lp = quad * 128 + lx * 8;

    // Q fragments (already split in workspace)
    bf16x8 qh[2][2], ql[2][2];
#pragma unroll
    for (int a = 0; a < 2; a++)
#pragma unroll
        for (int ks = 0; ks < 2; ks++) {
            const size_t fo = base + ((size_t)((q0 >> 4) + w * 2 + a) * 2 + ks) * 512 + lp;
            qh[a][ks] = *(const bf16x8*)(Qhi + fo);
            ql[a][ks] = *(const bf16x8*)(Qlo + fo);
        }

    f32x4 O[2][4];
    float l_part[2][4];
#pragma unroll
    for (int a = 0; a < 2; a++) {
#pragma unroll
        for (int dt = 0; dt < 4; dt++) O[a][dt] = (f32x4){0.f,0.f,0.f,0.f};
#pragma unroll
        for (int r = 0; r < 4; r++) l_part[a][r] = 0.f;
    }

#pragma unroll 1
    for (int kt = 0; kt < SEQ; kt += 64) {
        // ---- K fragments for this tile ----
        bf16x8 kh[2][4], kl[2][4];
#pragma unroll
        for (int c = 0; c < 4; c++)
#pragma unroll
            for (int ks = 0; ks < 2; ks++) {
                const size_t fo = base + ((size_t)((kt >> 4) + c) * 2 + ks) * 512 + lp;
                kh[ks][c] = *(const bf16x8*)(Khi + fo);
                kl[ks][c] = *(const bf16x8*)(Klo + fo);
            }

        // ---- scores + exp -> PS ----
#pragma unroll
        for (int a = 0; a < 2; a++) {
#pragma unroll
            for (int c = 0; c < 4; c++) {
                f32x4 acc = (f32x4){0.f,0.f,0.f,0.f};
#pragma unroll
                for (int ks = 0; ks < 2; ks++) {
                    acc = __builtin_amdgcn_mfma_f32_16x16x32_bf16(qh[a][ks], kh[ks][c], acc, 0, 0, 0);
                    acc = __builtin_amdgcn_mfma_f32_16x16x32_bf16(ql[a][ks], kh[ks][c], acc, 0, 0, 0);
                    acc = __builtin_amdgcn_mfma_f32_16x16x32_bf16(qh[a][ks], kl[ks][c], acc, 0, 0, 0);
                }
#pragma unroll
                for (int r = 0; r < 4; r++) {
                    float p = exp2f(acc[r] * 0.18033688011112042f);   // exp(s/8)
                    l_part[a][r] += p;
                    PS[w][a * 16 + quad * 4 + r][c * 16 + lx] = p;
                }
            }
        }

        // ---- V fragments ----
        bf16x8 vh[2][4], vl[2][4];
#pragma unroll
        for (int dt = 0; dt < 4; dt++)
#pragma unroll
            for (int ks2 = 0; ks2 < 2; ks2++) {
                const size_t fo = base + ((size_t)dt * 64 + (kt >> 5) + ks2) * 512 + lp;
                vh[ks2][dt] = *(const bf16x8*)(Vhi + fo);
                vl[ks2][dt] = *(const bf16x8*)(Vlo + fo);
            }

        // ---- PV ----
#pragma unroll
        for (int a = 0; a < 2; a++) {
#pragma unroll
            for (int ks2 = 0; ks2 < 2; ks2++) {
                const float* ps = &PS[w][a * 16 + lx][ks2 * 32 + quad * 8];
                float pf[8];
                *(float4*)&pf[0] = *(const float4*)ps;
                *(float4*)&pf[4] = *(const float4*)(ps + 4);
                bf16x8 phi, plo;
                split8(pf, phi, plo);
#pragma unroll
                for (int dt = 0; dt < 4; dt++) {
                    O[a][dt] = __builtin_amdgcn_mfma_f32_16x16x32_bf16(phi, vh[ks2][dt], O[a][dt], 0, 0, 0);
                    O[a][dt] = __builtin_amdgcn_mfma_f32_16x16x32_bf16(plo, vh[ks2][dt], O[a][dt], 0, 0, 0);
                    O[a][dt] = __builtin_amdgcn_mfma_f32_16x16x32_bf16(phi, vl[ks2][dt], O[a][dt], 0, 0, 0);
                }
            }
        }
    }

    float linv[2][4];
#pragma unroll
    for (int a = 0; a < 2; a++)
#pragma unroll
        for (int r = 0; r < 4; r++) {
            float l = l_part[a][r];
            l += __shfl_xor(l, 1);
            l += __shfl_xor(l, 2);
            l += __shfl_xor(l, 4);
            l += __shfl_xor(l, 8);
            linv[a][r] = 1.f / l;
        }

    float* Po = &PS[0][0][0];   // reuse as [128][68]
    __syncthreads();            // all waves done with their PS regions
#pragma unroll
    for (int a = 0; a < 2; a++)
#pragma unroll
        for (int dt = 0; dt < 4; dt++)
#pragma unroll
            for (int r = 0; r < 4; r++)
                Po[(size_t)(w * 32 + a * 16 + quad * 4 + r) * 68 + dt * 16 + lx] =
                    O[a][dt][r] * linv[a][r];
    __syncthreads();
    {
        const int q    = t >> 1;
        const int half = t & 1;
        const float* prow = Po + (size_t)q * 68 + half * 32;
        float* dst = OUT + ((size_t)(b * SEQ + q0 + q)) * HID + h * HDIM + half * 32;
#pragma unroll
        for (int e = 0; e < 8; e++)
            ((float4*)dst)[e] = ((const float4*)prow)[e];
    }
}

// ---------------------------------------------------------------------------
extern "C" void kernel_launch(void* const* d_in, const int* in_sizes, int n_in,
                              void* d_out, int out_size, void* d_ws, size_t ws_size,
                              hipStream_t stream)
{
    const float* X  = (const float*)d_in[0];
    const float* Wq = (const float*)d_in[1];
    const float* Wk = (const float*)d_in[2];
    const float* Wv = (const float*)d_in[3];
    float* out = (float*)d_out;

    const size_t qkv_elems = (size_t)BATCH * NHEADS * SEQ * HDIM;  // 4,194,304
    char* wsb = (char*)d_ws;
    float* ct  = (float*)wsb;                       // 0.5 MB
    float* st  = ct + (size_t)SEQ * HDIM;           // 0.5 MB
    u16* Xhi = (u16*)(st + (size_t)SEQ * HDIM);     // 8 MB
    u16* Xlo = Xhi + (size_t)NX;                    // 8 MB
    u16* Whi = Xlo + (size_t)NX;                    // 6 MB
    u16* Wlo = Whi + 3 * (size_t)NW;                // 6 MB
    u16* Qhi = Wlo + 3 * (size_t)NW;                // 8 MB
    u16* Qlo = Qhi + qkv_elems;                     // 8 MB
    u16* Khi = Qlo + qkv_elems;                     // 8 MB
    u16* Klo = Khi + qkv_elems;                     // 8 MB
    u16* Vhi = Klo + qkv_elems;                     // 8 MB
    u16* Vlo = Vhi + qkv_elems;                     // 8 MB   (total 77 MB)

    rope_tables_kernel<<<(SEQ * HDIM + 255) / 256, 256, 0, stream>>>(ct, st);

    const long tot = (long)NX + 3L * NW;
    split_kernel<<<(int)((tot / 4 + 255) / 256), 256, 0, stream>>>(
        X, Wq, Wk, Wv, Xhi, Xlo, Whi, Wlo);

    qkv_mfma_kernel<<<dim3(HID / 128, (BATCH * SEQ) / 128, 3), 256, 0, stream>>>(
        Xhi, Xlo, Whi, Wlo, ct, st, Qhi, Qlo, Khi, Klo, Vhi, Vlo);

    attn_kernel<<<dim3(SEQ / 128, NHEADS, BATCH), 256, 0, stream>>>(
        Qhi, Qlo, Khi, Klo, Vhi, Vlo, out);
}